// Round 1
// baseline (93.606 us; speedup 1.0000x reference)
//
#include <hip/hip_runtime.h>
#include <float.h>

// NearestCluster: per-batch NN argmin.
// coords1 [L1=4096, N=8, C=3] f32 (reference points)
// coords2 [L2=4096, N=8, C=3] f32 (query points)
// out int32: [L2*N] cluster idx (argmin over L1, per batch), then [L2*N] batch idx.
//
// Numerics: bit-exact replication of numpy f32 reference:
//   qq = (q0*q0 + q1*q1) + q2*q2          (round each op, no fma)
//   rr = (r0*r0 + r1*r1) + r2*r2
//   dot = ((q0*r0) + (q1*r1)) + (q2*r2)   (round each op, no fma)
//   d2 = (qq + rr) - 2*dot                (2*dot exact; single-round subtract
//                                          == __fmaf_rn(-2, dot, qq+rr))
// argmin ties -> lowest index (np.argmin first occurrence).
//
// R1: 32 KB LDS chunks (2 passes) -> 4 blocks/CU, 16 waves/CU, grid 1024.
// R2: LDS-BW was the bottleneck (1.07 GB LDS reads = ~98 B/clk/CU = 77% of the
//     128 B/clk peak; VALUBusy 62% = lgkmcnt stalls). Restructure: 32-lane
//     groups x 4 queries/thread -> each float4 ref read serves 4 distances
//     (8 B/dist -> 2-4 B/dist), plus wave-halves read identical addresses
//     (free broadcast). Grid/occupancy unchanged. Index tracked as iteration
//     counter, reconstructed at the end (j = 64*t + lane (+32)).

constexpr int kL1 = 4096, kL2 = 4096, kN = 8;
constexpr int kChunk = 2048;      // refs per LDS chunk -> 32 KB
constexpr int kQPerBlock = 32;    // 8 groups of 32 lanes x 4 queries
constexpr int kQ = 4;

__global__ __launch_bounds__(256, 4)
void nearest_kernel(const float* __restrict__ c1, const float* __restrict__ c2,
                    int* __restrict__ out) {
#pragma clang fp contract(off)
  __shared__ float4 refs[kChunk];  // x, y, z, rr

  const int tid = threadIdx.x;
  const int n = blockIdx.y;

  // ---- 32-lane groups; 4 queries per group ----
  const int g = tid >> 5;        // 0..7
  const int lane = tid & 31;     // 0..31
  const int q0 = blockIdx.x * kQPerBlock + g * kQ;

  float qx[kQ], qy[kQ], qz[kQ], qq[kQ];
#pragma unroll
  for (int i = 0; i < kQ; ++i) {
    const float* p = c2 + ((q0 + i) * kN + n) * 3;
    qx[i] = p[0]; qy[i] = p[1]; qz[i] = p[2];
    qq[i] = __fadd_rn(__fadd_rn(__fmul_rn(qx[i], qx[i]), __fmul_rn(qy[i], qy[i])),
                      __fmul_rn(qz[i], qz[i]));
  }

  // Two accumulator sets per query (ref slot A = lane, slot B = lane+32) for ILP.
  float bdA[kQ], bdB[kQ];
  int tA[kQ], tB[kQ];
#pragma unroll
  for (int i = 0; i < kQ; ++i) { bdA[i] = FLT_MAX; bdB[i] = FLT_MAX; tA[i] = 0; tB[i] = 0; }

  int tglob = 0;
  for (int chunk = 0; chunk < kL1 / kChunk; ++chunk) {
    __syncthreads();  // previous chunk's readers done before overwrite

    // ---- Stage chunk of coords1[:, n, :] into LDS with np-rounded rr ----
#pragma unroll
    for (int k = 0; k < kChunk / 256; ++k) {
      const int j = tid + 256 * k;
      const float* p = c1 + ((chunk * kChunk + j) * kN + n) * 3;
      const float r0 = p[0], r1 = p[1], r2 = p[2];
      const float rr = __fadd_rn(
          __fadd_rn(__fmul_rn(r0, r0), __fmul_rn(r1, r1)), __fmul_rn(r2, r2));
      refs[j] = make_float4(r0, r1, r2, rr);
    }
    __syncthreads();

#pragma unroll 2
    for (int t2 = 0; t2 < kChunk / 64; ++t2, ++tglob) {  // 32 iters/chunk
      const float4 rA = refs[t2 * 64 + lane];
      const float4 rB = refs[t2 * 64 + lane + 32];
#pragma unroll
      for (int i = 0; i < kQ; ++i) {
        const float dotA = __fadd_rn(
            __fadd_rn(__fmul_rn(qx[i], rA.x), __fmul_rn(qy[i], rA.y)),
            __fmul_rn(qz[i], rA.z));
        const float dA = __fmaf_rn(-2.0f, dotA, __fadd_rn(qq[i], rA.w));
        if (dA < bdA[i]) { bdA[i] = dA; tA[i] = tglob; }

        const float dotB = __fadd_rn(
            __fadd_rn(__fmul_rn(qx[i], rB.x), __fmul_rn(qy[i], rB.y)),
            __fmul_rn(qz[i], rB.z));
        const float dB = __fmaf_rn(-2.0f, dotB, __fadd_rn(qq[i], rB.w));
        if (dB < bdB[i]) { bdB[i] = dB; tB[i] = tglob; }
      }
    }
  }

  // ---- In-thread merge A vs B (index-aware: tie -> lower global j) ----
  float bd[kQ]; int bj[kQ];
#pragma unroll
  for (int i = 0; i < kQ; ++i) {
    const int jA = tA[i] * 64 + lane;
    const int jB = tB[i] * 64 + lane + 32;
    bd[i] = bdA[i]; bj[i] = jA;
    if (bdB[i] < bd[i] || (bdB[i] == bd[i] && jB < bj[i])) { bd[i] = bdB[i]; bj[i] = jB; }
  }

  // ---- Cross-lane merge over the 32-lane group (xor 1,2,4,8,16) ----
#pragma unroll
  for (int m = 1; m <= 16; m <<= 1) {
#pragma unroll
    for (int i = 0; i < kQ; ++i) {
      const float od = __shfl_xor(bd[i], m);
      const int oj = __shfl_xor(bj[i], m);
      if (od < bd[i] || (od == bd[i] && oj < bj[i])) { bd[i] = od; bj[i] = oj; }
    }
  }

  if (lane == 0) {
#pragma unroll
    for (int i = 0; i < kQ; ++i) {
      out[(q0 + i) * kN + n] = bj[i];
      out[kL2 * kN + (q0 + i) * kN + n] = n;
    }
  }
}

extern "C" void kernel_launch(void* const* d_in, const int* in_sizes, int n_in,
                              void* d_out, int out_size, void* d_ws, size_t ws_size,
                              hipStream_t stream) {
  const float* c1 = (const float*)d_in[0];
  const float* c2 = (const float*)d_in[1];
  int* out = (int*)d_out;
  dim3 grid(kL2 / kQPerBlock, kN);  // 128 x 8 = 1024 blocks
  nearest_kernel<<<grid, dim3(256), 0, stream>>>(c1, c2, out);
}

// Round 2
// 90.181 us; speedup vs baseline: 1.0380x; 1.0380x over previous
//
#include <hip/hip_runtime.h>
#include <float.h>

// NearestCluster: per-batch NN argmin.
// coords1 [L1=4096, N=8, C=3] f32 (reference points)
// coords2 [L2=4096, N=8, C=3] f32 (query points)
// out int32: [L2*N] cluster idx (argmin over L1, per batch), then [L2*N] batch idx.
//
// Numerics: bit-exact replication of numpy f32 reference:
//   qq = (q0*q0 + q1*q1) + q2*q2          (round each op, no fma)
//   rr = (r0*r0 + r1*r1) + r2*r2
//   dot = ((q0*r0) + (q1*r1)) + (q2*r2)   (round each op, no fma)
//   d2 = (qq + rr) - 2*dot                (2*dot exact; single-round subtract
//                                          == __fmaf_rn(-2, dot, qq+rr))
// v_pk_* f32 ops are per-element identical rounding -> packing is safe.
// argmin ties -> lowest index (np.argmin first occurrence): per-lane candidate
// j strictly ascending + strict < update; cross-lane merge is index-aware.
//
// R1: 32 KB LDS chunks, grid 1024 (4 blocks/CU, 16 waves/CU): 42.5 us,
//     VALUBusy 62%. Issue/latency-bound, NOT LDS-bound (LDS pipe ~48%).
// R2: scalarized kQ=4 rewrite lost the packed-f32 ops -> 48.5 us. Lesson:
//     v2f/pk math = 2 f32 per issue slot is load-bearing.
// R3: both fixes: (a) pk math with 4 queries/wave (3.5 pk + 3 upd per dist),
//     (b) grid 2048 via 16 q/block + 16 KB chunks -> 8 blocks/CU, 32 waves/CU
//     (grid was the occupancy cap, not LDS). launch_bounds(256,8) caps VGPR 64.

typedef float v2f __attribute__((ext_vector_type(2)));

constexpr int kL1 = 4096, kL2 = 4096, kN = 8;
constexpr int kChunk = 1024;      // refs per LDS chunk -> 16 KB
constexpr int kQPerBlock = 16;    // 4 waves x 4 queries
constexpr int kQ = 4;             // queries per wave

__global__ __launch_bounds__(256, 8)
void nearest_kernel(const float* __restrict__ c1, const float* __restrict__ c2,
                    int* __restrict__ out) {
#pragma clang fp contract(off)
  __shared__ float4 refs[kChunk];  // x, y, z, rr

  const int tid = threadIdx.x;
  const int n = blockIdx.y;
  const int wave = tid >> 6;     // 0..3
  const int lane = tid & 63;     // 0..63  (lane indexes refs)
  const int q0 = blockIdx.x * kQPerBlock + wave * kQ;

  // ---- 4 queries per wave, packed as 2 v2f pairs (wave-uniform values) ----
  float qx[kQ], qy[kQ], qz[kQ], qqv[kQ];
#pragma unroll
  for (int i = 0; i < kQ; ++i) {
    const float* p = c2 + ((q0 + i) * kN + n) * 3;
    qx[i] = p[0]; qy[i] = p[1]; qz[i] = p[2];
    qqv[i] = __fadd_rn(__fadd_rn(__fmul_rn(qx[i], qx[i]), __fmul_rn(qy[i], qy[i])),
                       __fmul_rn(qz[i], qz[i]));
  }
  const v2f qx01 = {qx[0], qx[1]}, qx23 = {qx[2], qx[3]};
  const v2f qy01 = {qy[0], qy[1]}, qy23 = {qy[2], qy[3]};
  const v2f qz01 = {qz[0], qz[1]}, qz23 = {qz[2], qz[3]};
  const v2f qq01 = {qqv[0], qqv[1]}, qq23 = {qqv[2], qqv[3]};

  float bd[kQ];
  int bi[kQ];
#pragma unroll
  for (int i = 0; i < kQ; ++i) { bd[i] = FLT_MAX; bi[i] = 0; }

  int jcur = lane;  // global ref index handled by this lane this iteration

  for (int chunk = 0; chunk < kL1 / kChunk; ++chunk) {
    __syncthreads();  // previous chunk's readers done before overwrite

    // ---- Stage chunk of coords1[:, n, :] into LDS with np-rounded rr ----
#pragma unroll
    for (int k = 0; k < kChunk / 256; ++k) {
      const int j = tid + 256 * k;
      const float* p = c1 + ((chunk * kChunk + j) * kN + n) * 3;
      const float r0 = p[0], r1 = p[1], r2 = p[2];
      const float rr = __fadd_rn(
          __fadd_rn(__fmul_rn(r0, r0), __fmul_rn(r1, r1)), __fmul_rn(r2, r2));
      refs[j] = make_float4(r0, r1, r2, rr);
    }
    __syncthreads();

#pragma unroll 2
    for (int t = 0; t < kChunk / 64; ++t) {  // 16 iters/chunk
      const float4 r = refs[t * 64 + lane];
      const v2f rx = {r.x, r.x};
      const v2f ry = {r.y, r.y};
      const v2f rz = {r.z, r.z};
      const v2f rw = {r.w, r.w};

      // queries 0,1
      {
        const v2f m0 = qx01 * rx;
        const v2f m1 = qy01 * ry;
        const v2f s01 = m0 + m1;
        const v2f m2 = qz01 * rz;
        const v2f dot = s01 + m2;
        const v2f A = qq01 + rw;
        const v2f d = __builtin_elementwise_fma((v2f){-2.0f, -2.0f}, dot, A);
        if (d.x < bd[0]) { bd[0] = d.x; bi[0] = jcur; }
        if (d.y < bd[1]) { bd[1] = d.y; bi[1] = jcur; }
      }
      // queries 2,3
      {
        const v2f m0 = qx23 * rx;
        const v2f m1 = qy23 * ry;
        const v2f s01 = m0 + m1;
        const v2f m2 = qz23 * rz;
        const v2f dot = s01 + m2;
        const v2f A = qq23 + rw;
        const v2f d = __builtin_elementwise_fma((v2f){-2.0f, -2.0f}, dot, A);
        if (d.x < bd[2]) { bd[2] = d.x; bi[2] = jcur; }
        if (d.y < bd[3]) { bd[3] = d.y; bi[3] = jcur; }
      }
      jcur += 64;
    }
  }

  // ---- Cross-lane merge over the full wave (xor 1..32), index-aware ----
#pragma unroll
  for (int m = 1; m <= 32; m <<= 1) {
#pragma unroll
    for (int i = 0; i < kQ; ++i) {
      const float od = __shfl_xor(bd[i], m);
      const int oj = __shfl_xor(bi[i], m);
      if (od < bd[i] || (od == bd[i] && oj < bi[i])) { bd[i] = od; bi[i] = oj; }
    }
  }

  if (lane == 0) {
#pragma unroll
    for (int i = 0; i < kQ; ++i) {
      out[(q0 + i) * kN + n] = bi[i];
      out[kL2 * kN + (q0 + i) * kN + n] = n;
    }
  }
}

extern "C" void kernel_launch(void* const* d_in, const int* in_sizes, int n_in,
                              void* d_out, int out_size, void* d_ws, size_t ws_size,
                              hipStream_t stream) {
  const float* c1 = (const float*)d_in[0];
  const float* c2 = (const float*)d_in[1];
  int* out = (int*)d_out;
  dim3 grid(kL2 / kQPerBlock, kN);  // 256 x 8 = 2048 blocks
  nearest_kernel<<<grid, dim3(256), 0, stream>>>(c1, c2, out);
}